// Round 1
// 121.124 us; speedup vs baseline: 1.0277x; 1.0277x over previous
//
#include <hip/hip_runtime.h>
#include <hip/hip_bf16.h>

// ---- problem constants ----
constexpr int NN = 16000, NE = 48000, NF = 32000;
constexpr int ND = 64, NB = 32, NG = 32;
constexpr int HIDN = 256, NCLS = 10;
constexpr int CHB = 32;                       // chunk-blocks per graph in k_ecc
constexpr int EFB = (NE + NF + 255) / 256;    // 313 scatter blocks (inside k_pre)
constexpr int PREB = (NN * ND) / 256;         // 4000 blocks in k_pre
constexpr int CAPE = 4096, CAPF = 4096;       // bucket capacity (mean 1500/1000)
constexpr float KLOG = 144.26950408889634f;   // 100 * log2(e)
constexpr float DLT  = 9.307710457348151f;    // (2/31) * KLOG
constexpr float INV_DLT = 0.10743849569269015f;
constexpr int HBINS = 39;                     // 4 pad + 32 real + 3 pad (alias-free taps)

// resolved append records (written by k_pre scatter, read by k_ecc)
struct alignas(8)  ERec { unsigned ab; float w; };               // a | b<<14
struct alignas(16) FRec { unsigned ab; unsigned c; float w; unsigned pad; };

// ---- ws word layout (~7.5 MB of the 268 MB ws) ----
constexpr int NH_OFF   = 0;                        // [NN*ND] f32 node heights
constexpr int ECCF_OFF = NH_OFF + NN * ND;         // [NG*NB*ND]=65536 f32 ecc
constexpr int CUR_OFF  = ECCF_OFF + NG * NB * ND;  // [64] u32 append cursors (memset)
constexpr int NOFS_OFF = CUR_OFF + 64;             // [33] i32 node boundaries (+pad)
constexpr int ER_OFF   = NOFS_OFF + 36;            // ERec[NG*CAPE], 16B-aligned
constexpr int FR_OFF   = ER_OFF + NG * CAPE * 2;   // FRec[NG*CAPF], 16B-aligned
constexpr int HB_OFF   = FR_OFF + NG * CAPF * 4;   // [NG*HIDN] f32 hidden acts
constexpr int ZERO_CNT = NG * NB * ND;             // eccf zeroed in k_pre

__device__ __forceinline__ int clamp_node(int n) {
    return ((unsigned)n < (unsigned)NN) ? n : 0;
}
template<bool BF> __device__ __forceinline__ float ldf(const void* p, int i) {
    return BF ? __bfloat162float(((const __hip_bfloat16*)p)[i]) : ((const float*)p)[i];
}
template<bool I64> __device__ __forceinline__ int ldi(const int* p, int i) {
    return I64 ? p[2 * i] : p[i];
}

// per-block dtype self-detection (wave-uniform via ballot)
__device__ __forceinline__ bool detect_bf(const void* xp) {
    const unsigned* xw = (const unsigned*)xp;
    unsigned w = xw[threadIdx.x & 63];
    return __ballot(((w >> 23) & 0xFFu) >= 200u) != 0ull;
}
__device__ __forceinline__ bool detect_i64(const int* eip) {
    const unsigned* eiw = (const unsigned*)eip;
    unsigned o = eiw[2 * (threadIdx.x & 63) + 1];
    return __ballot(o != 0u) == 0ull;
}

// 4-tap delta-histogram sigmoid, alias-free taps (rows (jlo+4)+0..3 distinct).
__device__ __forceinline__ void accum_hist(float h, float s, float* hb) {
    const float KDEC = __builtin_amdgcn_exp2f(-DLT);
    float hkL = fmaf(h, KLOG, KLOG);              // t_j = hkL - j*DLT
    float fl = floorf((hkL - 14.0f) * INV_DLT);
    int jlo = (int)fl + 1;                        // first j with t_j < 14
    if (jlo >= 32) return;                        // everything ~0
    if (jlo < -4) { hb[4 * 64] += s; return; }    // fully saturated: delta at bin 0
    float t0 = fmaf(-(fl + 1.0f), DLT, hkL);      // t at jlo, in [4.69, 14)
    float e  = __builtin_amdgcn_exp2f(t0);
    float s0 = __builtin_amdgcn_rcpf(1.0f + e);  e *= KDEC;
    float s1 = __builtin_amdgcn_rcpf(1.0f + e);  e *= KDEC;
    float s2 = __builtin_amdgcn_rcpf(1.0f + e);
    float* p = hb + (jlo + 4) * 64;
    float v0 = p[0], v1 = p[64], v2 = p[128], v3 = p[192];   // parallel ds_reads
    p[0]   = v0 + s * s0;
    p[64]  = v1 + s * (s1 - s0);
    p[128] = v2 + s * (s2 - s1);
    p[192] = v3 + s * (1.0f - s2);
}

// K0: fused prelude — heights, eccf zero, node boundaries, RESOLVED append-scatter.
template<bool BF, bool I64>
__device__ __forceinline__ void pre_body(const void* x, const void* nw, const void* v,
                                         const int* ei, const int* fc, const int* batch,
                                         const void* ew, const void* fw,
                                         float* wsf, int* wsi, unsigned* cur,
                                         ERec* er, FRec* fr,
                                         unsigned* cnt, unsigned* base) {
    int t = threadIdx.x;
    int gid = blockIdx.x * 256 + t;

    if (gid < ZERO_CNT) wsf[ECCF_OFF + gid] = 0.0f;

    if (gid < NN) {                                // node range boundaries
        int gn = ldi<I64>(batch, gid) & (NG - 1);
        int gp = (gid > 0) ? (ldi<I64>(batch, gid - 1) & (NG - 1)) : -1;
        for (int gg = gp + 1; gg <= gn; gg++) wsi[NOFS_OFF + gg] = gid;
        if (gid == NN - 1)
            for (int gg = gn + 1; gg <= NG; gg++) wsi[NOFS_OFF + gg] = NN;
    }

    {                                              // heights: gid in [0, NN*ND)
        int n = gid >> 6, d = gid & 63;
        float h = fmaf(ldf<BF>(x, n*3+2), ldf<BF>(v, 2*ND+d),
                  fmaf(ldf<BF>(x, n*3+1), ldf<BF>(v, ND+d),
                       ldf<BF>(x, n*3+0) * ldf<BF>(v, d))) * ldf<BF>(nw, n);
        wsf[NH_OFF + gid] = h;
    }

    if (blockIdx.x < EFB) {                        // append-scatter (block-uniform)
        if (t < 64) cnt[t] = 0;
        __syncthreads();
        int id = blockIdx.x * 256 + t;
        int bin = 0; unsigned rank = 0; bool act = false;
        if (id < NE + NF) {
            if (id < NE) bin = ldi<I64>(batch, clamp_node(ldi<I64>(ei, id))) & 31;
            else bin = 32 + (ldi<I64>(batch, clamp_node(ldi<I64>(fc, id - NE))) & 31);
            act = true;
            rank = atomicAdd(&cnt[bin], 1u);
        }
        __syncthreads();
        if (t < 64) base[t] = cnt[t] ? atomicAdd(&cur[t], cnt[t]) : 0u;
        __syncthreads();
        if (act) {
            int off = (int)(base[bin] + rank);
            if (bin < 32) {
                if (off < CAPE) {
                    unsigned a = (unsigned)clamp_node(ldi<I64>(ei, id));
                    unsigned b = (unsigned)clamp_node(ldi<I64>(ei, NE + id));
                    ERec r; r.ab = a | (b << 14); r.w = ldf<BF>(ew, id);
                    er[bin * CAPE + off] = r;
                }
            } else {
                if (off < CAPF) {
                    int fid = id - NE;
                    unsigned a = (unsigned)clamp_node(ldi<I64>(fc, fid));
                    unsigned b = (unsigned)clamp_node(ldi<I64>(fc, NF + fid));
                    unsigned c = (unsigned)clamp_node(ldi<I64>(fc, 2 * NF + fid));
                    FRec r; r.ab = a | (b << 14); r.c = c;
                    r.w = ldf<BF>(fw, fid); r.pad = 0u;
                    fr[(bin - 32) * CAPF + off] = r;
                }
            }
        }
    }
}
__global__ __launch_bounds__(256) void k_pre(const void* __restrict__ x,
                                             const void* __restrict__ nw,
                                             const void* __restrict__ v,
                                             const int* __restrict__ ei,
                                             const int* __restrict__ fc,
                                             const int* __restrict__ batch,
                                             const void* __restrict__ ew,
                                             const void* __restrict__ fw,
                                             float* __restrict__ wsf,
                                             int* __restrict__ wsi,
                                             unsigned* __restrict__ cur,
                                             ERec* __restrict__ er,
                                             FRec* __restrict__ fr) {
    __shared__ unsigned cnt[64], base[64];
    bool bf = detect_bf(x), i64 = detect_i64(ei);
    if (bf)  { if (i64) pre_body<true,true >(x,nw,v,ei,fc,batch,ew,fw,wsf,wsi,cur,er,fr,cnt,base);
               else     pre_body<true,false>(x,nw,v,ei,fc,batch,ew,fw,wsf,wsi,cur,er,fr,cnt,base); }
    else     { if (i64) pre_body<false,true >(x,nw,v,ei,fc,batch,ew,fw,wsf,wsi,cur,er,fr,cnt,base);
               else     pre_body<false,false>(x,nw,v,ei,fc,batch,ew,fw,wsf,wsi,cur,er,fr,cnt,base); }
}

// K1: ecc via wave-private LDS delta-histograms; records resolve the gather
// chain to {rec load -> nh gathers}, with records prefetched one unroll-batch
// ahead so steady-state latency per 4 elements is one L2 hop.
// Dtype-independent (records carry f32 weights; nh is f32).
__global__ __launch_bounds__(256, 4) void k_ecc(const float* __restrict__ nh,
                                                const int* __restrict__ wsi,
                                                const unsigned* __restrict__ cur,
                                                float* __restrict__ eccf,
                                                const ERec* __restrict__ er,
                                                const FRec* __restrict__ fr) {
    __shared__ float hist[4 * HBINS * 64];         // 39.9 KB; 4 blocks/CU = 159.7 KB
    int t = threadIdx.x;
    int d = t & 63;
    int w = __builtin_amdgcn_readfirstlane(t) >> 6;
    int g  = blockIdx.x >> 5;                 // / CHB
    int cb = blockIdx.x & (CHB - 1);
    int sid = cb * 4 + w;
    const int S = CHB * 4;                    // 128 streams per graph

    for (int j = t; j < 4 * HBINS * 64; j += 256) hist[j] = 0.0f;
    __syncthreads();

    float* hb = hist + w * (HBINS * 64) + d;  // wave-private copy, lane-owned column

    // nodes (+1), unroll 4 (direct contiguous rows, no chain)
    int ns = wsi[NOFS_OFF + g], nend = wsi[NOFS_OFF + g + 1];
    int i = ns + sid;
    for (; i + 3 * S < nend; i += 4 * S) {
        float h1 = nh[i * ND + d];
        float h2 = nh[(i + S) * ND + d];
        float h3 = nh[(i + 2 * S) * ND + d];
        float h4 = nh[(i + 3 * S) * ND + d];
        accum_hist(h1, 1.0f, hb);
        accum_hist(h2, 1.0f, hb);
        accum_hist(h3, 1.0f, hb);
        accum_hist(h4, 1.0f, hb);
    }
    for (; i < nend; i += S) accum_hist(nh[i * ND + d], 1.0f, hb);

    // edges (-1), unroll 4, records prefetched one batch ahead
    int ecnt = min((int)cur[g], CAPE);
    const ERec* eg = er + g * CAPE;
    i = sid;
    if (i + 3 * S < ecnt) {
        ERec r1 = eg[i], r2 = eg[i + S], r3 = eg[i + 2 * S], r4 = eg[i + 3 * S];
        for (;;) {
            int ni = i + 4 * S;
            bool more = (ni + 3 * S < ecnt);
            // issue the 8 gathers for the current batch immediately
            float a1 = nh[(r1.ab & 16383) * ND + d], b1 = nh[((r1.ab >> 14) & 16383) * ND + d];
            float a2 = nh[(r2.ab & 16383) * ND + d], b2 = nh[((r2.ab >> 14) & 16383) * ND + d];
            float a3 = nh[(r3.ab & 16383) * ND + d], b3 = nh[((r3.ab >> 14) & 16383) * ND + d];
            float a4 = nh[(r4.ab & 16383) * ND + d], b4 = nh[((r4.ab >> 14) & 16383) * ND + d];
            ERec n1, n2, n3, n4;
            if (more) { n1 = eg[ni]; n2 = eg[ni + S]; n3 = eg[ni + 2 * S]; n4 = eg[ni + 3 * S]; }
            accum_hist(fmaxf(a1, b1) * r1.w, -1.0f, hb);
            accum_hist(fmaxf(a2, b2) * r2.w, -1.0f, hb);
            accum_hist(fmaxf(a3, b3) * r3.w, -1.0f, hb);
            accum_hist(fmaxf(a4, b4) * r4.w, -1.0f, hb);
            i = ni;
            if (!more) break;
            r1 = n1; r2 = n2; r3 = n3; r4 = n4;
        }
    }
    for (; i < ecnt; i += S) {
        ERec r = eg[i];
        float ha = nh[(r.ab & 16383) * ND + d], hbv = nh[((r.ab >> 14) & 16383) * ND + d];
        accum_hist(fmaxf(ha, hbv) * r.w, -1.0f, hb);
    }

    // faces (+1), unroll 4, prefetched
    int fcnt = min((int)cur[32 + g], CAPF);
    const FRec* fg = fr + g * CAPF;
    i = sid;
    if (i + 3 * S < fcnt) {
        FRec r1 = fg[i], r2 = fg[i + S], r3 = fg[i + 2 * S], r4 = fg[i + 3 * S];
        for (;;) {
            int ni = i + 4 * S;
            bool more = (ni + 3 * S < fcnt);
            float a1 = nh[(r1.ab & 16383) * ND + d], b1 = nh[((r1.ab >> 14) & 16383) * ND + d];
            float c1 = nh[r1.c * ND + d];
            float a2 = nh[(r2.ab & 16383) * ND + d], b2 = nh[((r2.ab >> 14) & 16383) * ND + d];
            float c2 = nh[r2.c * ND + d];
            float a3 = nh[(r3.ab & 16383) * ND + d], b3 = nh[((r3.ab >> 14) & 16383) * ND + d];
            float c3 = nh[r3.c * ND + d];
            float a4 = nh[(r4.ab & 16383) * ND + d], b4 = nh[((r4.ab >> 14) & 16383) * ND + d];
            float c4 = nh[r4.c * ND + d];
            FRec n1, n2, n3, n4;
            if (more) { n1 = fg[ni]; n2 = fg[ni + S]; n3 = fg[ni + 2 * S]; n4 = fg[ni + 3 * S]; }
            accum_hist(fmaxf(fmaxf(a1, b1), c1) * r1.w, 1.0f, hb);
            accum_hist(fmaxf(fmaxf(a2, b2), c2) * r2.w, 1.0f, hb);
            accum_hist(fmaxf(fmaxf(a3, b3), c3) * r3.w, 1.0f, hb);
            accum_hist(fmaxf(fmaxf(a4, b4), c4) * r4.w, 1.0f, hb);
            i = ni;
            if (!more) break;
            r1 = n1; r2 = n2; r3 = n3; r4 = n4;
        }
    }
    for (; i < fcnt; i += S) {
        FRec r = fg[i];
        float ha = nh[(r.ab & 16383) * ND + d], hbv = nh[((r.ab >> 14) & 16383) * ND + d];
        float hc = nh[r.c * ND + d];
        accum_hist(fmaxf(fmaxf(ha, hbv), hc) * r.w, 1.0f, hb);
    }

    __syncthreads();
    // collapse 4 wave copies, then prefix over rows; one atomic per (j,d).
    for (int o = t; o < HBINS * 64; o += 256)
        hist[o] += hist[HBINS*64 + o] + hist[2*HBINS*64 + o] + hist[3*HBINS*64 + o];
    __syncthreads();
    if (t < 64) {
        float run = hist[t] + hist[64 + t] + hist[128 + t] + hist[192 + t];
        float* eb = eccf + g * (NB * ND) + t;
        for (int j = 0; j < 32; j++) {
            run += hist[(j + 4) * 64 + t];
            atomicAdd(eb + j * 64, run);
        }
    }
}

// K2: MLP layer 1 + fused flat-output flush. grid = 32 graphs x 8 hid-chunks.
template<bool BF>
__device__ __forceinline__ void mlp1_body(const void* W1, const void* b1,
                                          const float* eccf, float* hbuf,
                                          void* outv, float* red, float* pr) {
    int g = blockIdx.x >> 3, hc = blockIdx.x & 7;
    int t = threadIdx.x;

    const float4* fp = (const float4*)(eccf + g * (NB * ND) + t * 8);
    float4 fa = fp[0], fb = fp[1];
    float fl[8] = {fa.x, fa.y, fa.z, fa.w, fb.x, fb.y, fb.z, fb.w};

    if (hc == 0) {                              // flush flat output (once per graph)
        int ob = NG * NCLS + g * (NB * ND) + t * 8;
        if (BF) {
#pragma unroll
            for (int j = 0; j < 8; j++)
                ((__hip_bfloat16*)outv)[ob + j] = __float2bfloat16(fl[j]);
        } else {
            ((float4*)((float*)outv + ob))[0] = fa;
            ((float4*)((float*)outv + ob))[1] = fb;
        }
    }

    float acc[32];
#pragma unroll
    for (int r = 0; r < 32; r++) acc[r] = 0.0f;
#pragma unroll 4
    for (int r = 0; r < 32; r++) {
        size_t wb = (size_t)(hc * 32 + r) * (NB * ND) + t * 8;
        float wv[8];
        if (BF) {
            uint4 u = *(const uint4*)((const __hip_bfloat16*)W1 + wb);
            wv[0] = __uint_as_float(u.x << 16); wv[1] = __uint_as_float(u.x & 0xffff0000u);
            wv[2] = __uint_as_float(u.y << 16); wv[3] = __uint_as_float(u.y & 0xffff0000u);
            wv[4] = __uint_as_float(u.z << 16); wv[5] = __uint_as_float(u.z & 0xffff0000u);
            wv[6] = __uint_as_float(u.w << 16); wv[7] = __uint_as_float(u.w & 0xffff0000u);
        } else {
            float4 a = *(const float4*)((const float*)W1 + wb);
            float4 b = *(const float4*)((const float*)W1 + wb + 4);
            wv[0]=a.x; wv[1]=a.y; wv[2]=a.z; wv[3]=a.w;
            wv[4]=b.x; wv[5]=b.y; wv[6]=b.z; wv[7]=b.w;
        }
        float s = 0.0f;
#pragma unroll
        for (int j = 0; j < 8; j++) s = fmaf(wv[j], fl[j], s);
        acc[r] = s;
    }

#pragma unroll
    for (int r = 0; r < 32; r++) red[t * 33 + r] = acc[r];
    __syncthreads();
    {
        int r = t >> 3, s8 = t & 7;
        float sum = 0.0f;
#pragma unroll
        for (int i = 0; i < 32; i++) sum += red[(s8 * 32 + i) * 33 + r];
        pr[r * 8 + s8] = sum;
    }
    __syncthreads();
    if (t < 32) {
        float h = ldf<BF>(b1, hc * 32 + t);
#pragma unroll
        for (int s8 = 0; s8 < 8; s8++) h += pr[t * 8 + s8];
        hbuf[g * HIDN + hc * 32 + t] = fmaxf(h, 0.0f);
    }
}
__global__ __launch_bounds__(256) void k_mlp1(const void* __restrict__ W1,
                                              const void* __restrict__ b1,
                                              const float* __restrict__ eccf,
                                              float* __restrict__ hbuf,
                                              void* __restrict__ outv,
                                              const void* __restrict__ x) {
    __shared__ float red[256 * 33];
    __shared__ float pr[256];
    if (detect_bf(x)) mlp1_body<true>(W1, b1, eccf, hbuf, outv, red, pr);
    else              mlp1_body<false>(W1, b1, eccf, hbuf, outv, red, pr);
}

// K3: MLP layer 2. one block per graph; wave per class, shuffle reduce.
template<bool BF>
__device__ __forceinline__ void mlp2_body(const void* W2, const void* b2,
                                          const float* hbuf, void* outv, float* hs) {
    int g = blockIdx.x, t = threadIdx.x;
    hs[t] = hbuf[g * HIDN + t];
    __syncthreads();
    int w = t >> 6, lane = t & 63;
    for (int c = w; c < NCLS; c += 4) {
        float p = hs[lane]        * ldf<BF>(W2, c * HIDN + lane)
                + hs[lane + 64]   * ldf<BF>(W2, c * HIDN + lane + 64)
                + hs[lane + 128]  * ldf<BF>(W2, c * HIDN + lane + 128)
                + hs[lane + 192]  * ldf<BF>(W2, c * HIDN + lane + 192);
#pragma unroll
        for (int off = 32; off >= 1; off >>= 1) p += __shfl_xor(p, off);
        if (lane == 0) {
            float r = p + ldf<BF>(b2, c);
            if (BF) ((__hip_bfloat16*)outv)[g * NCLS + c] = __float2bfloat16(r);
            else    ((float*)outv)[g * NCLS + c] = r;
        }
    }
}
__global__ __launch_bounds__(256) void k_mlp2(const void* __restrict__ W2,
                                              const void* __restrict__ b2,
                                              const float* __restrict__ hbuf,
                                              void* __restrict__ outv,
                                              const void* __restrict__ x) {
    __shared__ float hs[HIDN];
    if (detect_bf(x)) mlp2_body<true>(W2, b2, hbuf, outv, hs);
    else              mlp2_body<false>(W2, b2, hbuf, outv, hs);
}

extern "C" void kernel_launch(void* const* d_in, const int* in_sizes, int n_in,
                              void* d_out, int out_size, void* d_ws, size_t ws_size,
                              hipStream_t stream) {
    const void* x  = d_in[0];
    const void* nw = d_in[1];
    const void* ew = d_in[2];
    const void* fw = d_in[3];
    const void* v  = d_in[4];
    const void* W1 = d_in[5];
    const void* b1 = d_in[6];
    const void* W2 = d_in[7];
    const void* b2 = d_in[8];
    const int* ei    = (const int*)d_in[9];
    const int* fc    = (const int*)d_in[10];
    const int* batch = (const int*)d_in[11];

    float*    wsf = (float*)d_ws;
    unsigned* wsu = (unsigned*)d_ws;
    int*      wsi = (int*)d_ws;
    float*    nh   = wsf + NH_OFF;
    float*    eccf = wsf + ECCF_OFF;
    unsigned* cur  = wsu + CUR_OFF;
    float*    hbuf = wsf + HB_OFF;
    ERec*     er   = (ERec*)(wsf + ER_OFF);
    FRec*     fr   = (FRec*)(wsf + FR_OFF);

    // zero append cursors (256 B)
    hipMemsetAsync((char*)d_ws + (size_t)CUR_OFF * 4, 0, 64 * 4, stream);

    k_pre<<<PREB, 256, 0, stream>>>(x, nw, v, ei, fc, batch, ew, fw, wsf, wsi, cur, er, fr);
    k_ecc<<<NG * CHB, 256, 0, stream>>>(nh, wsi, cur, eccf, er, fr);
    k_mlp1<<<NG * 8, 256, 0, stream>>>(W1, b1, eccf, hbuf, d_out, x);
    k_mlp2<<<NG, 256, 0, stream>>>(W2, b2, hbuf, d_out, x);
}